// Round 5
// baseline (220.684 us; speedup 1.0000x reference)
//
#include <hip/hip_runtime.h>
#include <hip/hip_bf16.h>

// ---------------------------------------------------------------------------
// MultiHeadedMaskedSelfAttention (B=2,T=2048,C=768,H=12,D=64).
// I/O: float32. Compute: bf16 MFMA with hi/lo compensation on the
// softmax-critical path (x->Q/K and Q.K^T), plain bf16 elsewhere.
// attn_fwd v4: 16-row waves (qf dimension deleted from the verified body).
// grid 1536 x 128thr = 2 waves/block, waves pair fragments {f, 127-f}
// (33 tile-units flat); 8-XCD grouping (3 heads per XCD, K/V L2-resident).
// 6 blocks/CU exactly -> 12 waves/CU (vs 6 uneven before).
// ---------------------------------------------------------------------------

typedef float f32x4 __attribute__((ext_vector_type(4)));
typedef short s16x8 __attribute__((ext_vector_type(8)));

#define MFMA(a, b, c) __builtin_amdgcn_mfma_f32_16x16x32_bf16((a), (b), (c), 0, 0, 0)

constexpr int Bb = 2, Tt = 2048, Cc = 768, Hh = 12, Dd = 64;
constexpr int Mm = Bb * Tt;   // 4096
constexpr int BH = Bb * Hh;   // 24

__device__ __forceinline__ void gload16(const void* g, void* l) {
  __builtin_amdgcn_global_load_lds((const __attribute__((address_space(1))) void*)g,
                                   (__attribute__((address_space(3))) void*)l, 16, 0, 0);
}

__device__ __forceinline__ short f2bfbits(float f) {
  __hip_bfloat16 h = __float2bfloat16(f);
  return __builtin_bit_cast(short, h);
}
__device__ __forceinline__ float bf2f(short s) {
  __hip_bfloat16 h = __builtin_bit_cast(__hip_bfloat16, s);
  return __bfloat162float(h);
}

// ---------------------------------------------------------------------------
// prep_x: x f32 [4096][768] -> Xhi, Xlo bf16. grid(1536), 256 thr, 8 elts/thr.
// ---------------------------------------------------------------------------
__global__ __launch_bounds__(256) void prep_x(const float* __restrict__ x,
                                              __hip_bfloat16* __restrict__ xhi,
                                              __hip_bfloat16* __restrict__ xlo) {
  const size_t i = ((size_t)blockIdx.x * 256 + threadIdx.x) * 8;
  float4 a = *reinterpret_cast<const float4*>(x + i);
  float4 b = *reinterpret_cast<const float4*>(x + i + 4);
  float v[8] = {a.x, a.y, a.z, a.w, b.x, b.y, b.z, b.w};
  s16x8 hi, lo;
#pragma unroll
  for (int j = 0; j < 8; ++j) {
    short h = f2bfbits(v[j]);
    hi[j] = h;
    lo[j] = f2bfbits(v[j] - bf2f(h));
  }
  *reinterpret_cast<s16x8*>((short*)xhi + i) = hi;
  *reinterpret_cast<s16x8*>((short*)xlo + i) = lo;
}

// ---------------------------------------------------------------------------
// prep_w: f32 [768][768] -> transposed bf16. z=0: wq (hi+lo), z=1: wk (hi+lo),
// z=2: wv (hi), z=3: linear (hi). grid (12,12,4), 256 thr, 64x64 tiles.
// ---------------------------------------------------------------------------
__global__ __launch_bounds__(256) void prep_w(
    const float* __restrict__ s0, const float* __restrict__ s1,
    const float* __restrict__ s2, const float* __restrict__ s3,
    __hip_bfloat16* __restrict__ h0, __hip_bfloat16* __restrict__ l0,
    __hip_bfloat16* __restrict__ h1, __hip_bfloat16* __restrict__ l1,
    __hip_bfloat16* __restrict__ h2, __hip_bfloat16* __restrict__ h3) {
  const float* src;
  __hip_bfloat16 *dh, *dl = nullptr;
  switch (blockIdx.z) {
    case 0: src = s0; dh = h0; dl = l0; break;
    case 1: src = s1; dh = h1; dl = l1; break;
    case 2: src = s2; dh = h2; break;
    default: src = s3; dh = h3; break;
  }
  __shared__ float tile[64][65];
  const int r0 = blockIdx.y * 64, c0 = blockIdx.x * 64;
  const int tid = threadIdx.x;
  const int rr = tid >> 4, c4 = (tid & 15) * 4;
#pragma unroll
  for (int it = 0; it < 4; ++it) {
    float4 v = *reinterpret_cast<const float4*>(src + (size_t)(r0 + rr + it * 16) * Cc + c0 + c4);
    tile[rr + it * 16][c4 + 0] = v.x;
    tile[rr + it * 16][c4 + 1] = v.y;
    tile[rr + it * 16][c4 + 2] = v.z;
    tile[rr + it * 16][c4 + 3] = v.w;
  }
  __syncthreads();
#pragma unroll
  for (int it = 0; it < 2; ++it) {
    const int id = tid + it * 256;          // 0..511
    const int n = id >> 3, ch = (id & 7) * 8;
    s16x8 hi, lo;
#pragma unroll
    for (int j = 0; j < 8; ++j) {
      float v = tile[ch + j][n];
      short h = f2bfbits(v);
      hi[j] = h;
      lo[j] = f2bfbits(v - bf2f(h));
    }
    *reinterpret_cast<s16x8*>(dh + (size_t)(c0 + n) * Cc + r0 + ch) = hi;
    if (dl) *reinterpret_cast<s16x8*>(dl + (size_t)(c0 + n) * Cc + r0 + ch) = lo;
  }
}

// ---------------------------------------------------------------------------
// 128x128 GEMM cores. A[M,K] * Bt[N,K]^T, K=768, BK=32, 4 waves.
// ---------------------------------------------------------------------------
__device__ __forceinline__ void gemm128_core(const __hip_bfloat16* __restrict__ A,
                                             const __hip_bfloat16* __restrict__ Bt,
                                             int m0, int n0,
                                             short* ldsA, short* ldsB,
                                             f32x4 acc[4][4]) {
  const int tid = threadIdx.x;
  const int w = tid >> 6, l = tid & 63;
  const int wr = w >> 1, wc = w & 1;
  const int srow = l >> 2;
  const int scol = (l & 3) << 3;

  for (int kt = 0; kt < Cc / 32; ++kt) {
    const int kk = kt << 5;
#pragma unroll
    for (int i = 0; i < 2; ++i) {
      const int r = (w << 5) + (i << 4);
      gload16(A + (size_t)(m0 + r + srow) * Cc + kk + scol, ldsA + r * 32);
      gload16(Bt + (size_t)(n0 + r + srow) * Cc + kk + scol, ldsB + r * 32);
    }
    __syncthreads();
    s16x8 af[4], bfr[4];
#pragma unroll
    for (int i = 0; i < 4; ++i) {
      af[i]  = *reinterpret_cast<const s16x8*>(ldsA + ((wr << 6) + (i << 4) + (l & 15)) * 32 + ((l >> 4) << 3));
      bfr[i] = *reinterpret_cast<const s16x8*>(ldsB + ((wc << 6) + (i << 4) + (l & 15)) * 32 + ((l >> 4) << 3));
    }
#pragma unroll
    for (int i = 0; i < 4; ++i)
#pragma unroll
      for (int j = 0; j < 4; ++j)
        acc[i][j] = MFMA(af[i], bfr[j], acc[i][j]);
    __syncthreads();
  }
}

// hi/lo compensated: acc += Ahi*Bhi + (lo ? Ahi*Blo + Alo*Bhi : 0)
__device__ __forceinline__ void gemm128_hilo(
    const __hip_bfloat16* __restrict__ Ahi, const __hip_bfloat16* __restrict__ Alo,
    const __hip_bfloat16* __restrict__ Bhi, const __hip_bfloat16* __restrict__ Blo,
    bool lo, int m0, int n0, short* lds, f32x4 acc[4][4]) {
  short* ldsAh = lds;
  short* ldsAl = lds + 4096;
  short* ldsBh = lds + 8192;
  short* ldsBl = lds + 12288;
  const int tid = threadIdx.x;
  const int w = tid >> 6, l = tid & 63;
  const int wr = w >> 1, wc = w & 1;
  const int srow = l >> 2;
  const int scol = (l & 3) << 3;

  for (int kt = 0; kt < Cc / 32; ++kt) {
    const int kk = kt << 5;
#pragma unroll
    for (int i = 0; i < 2; ++i) {
      const int r = (w << 5) + (i << 4);
      const size_t aoff = (size_t)(m0 + r + srow) * Cc + kk + scol;
      const size_t boff = (size_t)(n0 + r + srow) * Cc + kk + scol;
      gload16(Ahi + aoff, ldsAh + r * 32);
      gload16(Bhi + boff, ldsBh + r * 32);
      if (lo) {
        gload16(Alo + aoff, ldsAl + r * 32);
        gload16(Blo + boff, ldsBl + r * 32);
      }
    }
    __syncthreads();
    s16x8 ah[4], bh[4], al[4], bl[4];
#pragma unroll
    for (int i = 0; i < 4; ++i) {
      const int ao = ((wr << 6) + (i << 4) + (l & 15)) * 32 + ((l >> 4) << 3);
      const int bo = ((wc << 6) + (i << 4) + (l & 15)) * 32 + ((l >> 4) << 3);
      ah[i] = *reinterpret_cast<const s16x8*>(ldsAh + ao);
      bh[i] = *reinterpret_cast<const s16x8*>(ldsBh + bo);
      if (lo) {
        al[i] = *reinterpret_cast<const s16x8*>(ldsAl + ao);
        bl[i] = *reinterpret_cast<const s16x8*>(ldsBl + bo);
      }
    }
#pragma unroll
    for (int i = 0; i < 4; ++i)
#pragma unroll
      for (int j = 0; j < 4; ++j)
        acc[i][j] = MFMA(ah[i], bh[j], acc[i][j]);
    if (lo) {
#pragma unroll
      for (int i = 0; i < 4; ++i)
#pragma unroll
        for (int j = 0; j < 4; ++j) {
          acc[i][j] = MFMA(ah[i], bl[j], acc[i][j]);
          acc[i][j] = MFMA(al[i], bh[j], acc[i][j]);
        }
    }
    __syncthreads();
  }
}

// ---------------------------------------------------------------------------
// QKV projection. grid (32, 6, 3): z=0 -> Q(hi,lo), z=1 -> K(hi,lo), z=2 -> V.
// Outputs in [B,H,T,D] layout.
// ---------------------------------------------------------------------------
__global__ __launch_bounds__(256) void qkv_gemm(
    const __hip_bfloat16* __restrict__ Xhi, const __hip_bfloat16* __restrict__ Xlo,
    const __hip_bfloat16* __restrict__ WqThi, const __hip_bfloat16* __restrict__ WqTlo,
    const __hip_bfloat16* __restrict__ WkThi, const __hip_bfloat16* __restrict__ WkTlo,
    const __hip_bfloat16* __restrict__ WvThi,
    __hip_bfloat16* __restrict__ Qhi, __hip_bfloat16* __restrict__ Qlo,
    __hip_bfloat16* __restrict__ Khi, __hip_bfloat16* __restrict__ Klo,
    __hip_bfloat16* __restrict__ V) {
  __shared__ __align__(16) short lds[16384];
  const int z = blockIdx.z;
  const bool lo = (z < 2);
  const __hip_bfloat16* Bhi = (z == 0) ? WqThi : (z == 1) ? WkThi : WvThi;
  const __hip_bfloat16* Blo = (z == 0) ? WqTlo : WkTlo;
  const int m0 = blockIdx.x * 128, n0 = blockIdx.y * 128;

  f32x4 acc[4][4];
#pragma unroll
  for (int i = 0; i < 4; ++i)
#pragma unroll
    for (int j = 0; j < 4; ++j) acc[i][j] = f32x4{0.f, 0.f, 0.f, 0.f};

  gemm128_hilo(Xhi, Xlo, Bhi, Blo, lo, m0, n0, lds, acc);

  const int tid = threadIdx.x, w = tid >> 6, l = tid & 63;
  const int wr = w >> 1, wc = w & 1;
#pragma unroll
  for (int i = 0; i < 4; ++i) {
#pragma unroll
    for (int j = 0; j < 4; ++j) {
#pragma unroll
      for (int r = 0; r < 4; ++r) {
        const int m = m0 + (wr << 6) + (i << 4) + ((l >> 4) << 2) + r;
        const int n = n0 + (wc << 6) + (j << 4) + (l & 15);
        const float v = acc[i][j][r];
        const int b = m >> 11, t = m & 2047, h = n >> 6, d = n & 63;
        const size_t idx = (((size_t)(b * Hh + h)) * Tt + t) * Dd + d;
        if (z == 2) {
          V[idx] = __float2bfloat16(v);
        } else {
          short hbits = f2bfbits(v);
          short lbits = f2bfbits(v - bf2f(hbits));
          if (z == 0) { ((short*)Qhi)[idx] = hbits; ((short*)Qlo)[idx] = lbits; }
          else        { ((short*)Khi)[idx] = hbits; ((short*)Klo)[idx] = lbits; }
        }
      }
    }
  }
}

// ---------------------------------------------------------------------------
// Output projection: out[M,C] (f32) = O[M,C](bf16) * LT[C,C]^T(bf16). grid(32,6)
// ---------------------------------------------------------------------------
__global__ __launch_bounds__(256) void proj_gemm(
    const __hip_bfloat16* __restrict__ O, const __hip_bfloat16* __restrict__ LT,
    float* __restrict__ out) {
  __shared__ __align__(16) short lds[8192];
  const int m0 = blockIdx.x * 128, n0 = blockIdx.y * 128;
  f32x4 acc[4][4];
#pragma unroll
  for (int i = 0; i < 4; ++i)
#pragma unroll
    for (int j = 0; j < 4; ++j) acc[i][j] = f32x4{0.f, 0.f, 0.f, 0.f};

  gemm128_core(O, LT, m0, n0, lds, lds + 4096, acc);

  const int tid = threadIdx.x, w = tid >> 6, l = tid & 63;
  const int wr = w >> 1, wc = w & 1;
#pragma unroll
  for (int i = 0; i < 4; ++i)
#pragma unroll
    for (int j = 0; j < 4; ++j)
#pragma unroll
      for (int r = 0; r < 4; ++r) {
        const int m = m0 + (wr << 6) + (i << 4) + ((l >> 4) << 2) + r;
        const int n = n0 + (wc << 6) + (j << 4) + (l & 15);
        out[(size_t)m * Cc + n] = acc[i][j][r];
      }
}

// ---------------------------------------------------------------------------
// V [BH][T][D] -> VT [BH][D][T].  grid (32, 24), 256 threads.
// ---------------------------------------------------------------------------
__global__ __launch_bounds__(256) void transpose_v(
    const __hip_bfloat16* __restrict__ V, __hip_bfloat16* __restrict__ VT) {
  __shared__ __align__(16) short tile[64][72];
  const int t0 = blockIdx.x * 64, bh = blockIdx.y;
  const __hip_bfloat16* src = V + (size_t)bh * Tt * Dd;
  __hip_bfloat16* dst = VT + (size_t)bh * Dd * Tt;
  const int tid = threadIdx.x;
  const int rr = tid >> 3;
  const int cc = (tid & 7) << 3;
#pragma unroll
  for (int it = 0; it < 2; ++it) {
    const int r = rr + it * 32;
    *reinterpret_cast<s16x8*>(&tile[r][cc]) =
        *reinterpret_cast<const s16x8*>(src + (size_t)(t0 + r) * Dd + cc);
  }
  __syncthreads();
#pragma unroll
  for (int it = 0; it < 2; ++it) {
    const int d = rr + it * 32;
    s16x8 o;
#pragma unroll
    for (int j = 0; j < 8; ++j) o[j] = tile[cc + j][d];
    *reinterpret_cast<s16x8*>(dst + (size_t)d * Tt + t0 + cc) = o;
  }
}

// ---------------------------------------------------------------------------
// Causal flash attention v4. grid (1536) x 128 threads (2 waves).
// Block i: xcd = i&7; j = i>>3 (0..191); bh = (i&7)*3 + j/64; f = j&63.
// Wave 0 -> fragment f (rows 16f..16f+15); wave 1 -> fragment 127-f.
// Per-block work = tiles(f)+tiles(127-f) = 33 (flat). Body = round-2/4
// verified code with the qf dimension deleted (single 16-row fragment).
// ---------------------------------------------------------------------------
__global__ __launch_bounds__(128) void attn_fwd(
    const __hip_bfloat16* __restrict__ Qhi, const __hip_bfloat16* __restrict__ Qlo,
    const __hip_bfloat16* __restrict__ Khi, const __hip_bfloat16* __restrict__ Klo,
    const __hip_bfloat16* __restrict__ VT, __hip_bfloat16* __restrict__ O) {
  __shared__ __align__(16) short pbuf[2][16 * 72];
  const int i = blockIdx.x;
  const int j = i >> 3;                       // 0..191
  const int bh = (i & 7) * 3 + (j >> 6);      // 0..23
  const int f = j & 63;                       // 0..63
  const int b = bh / Hh, h = bh % Hh;
  const int tid = threadIdx.x, w = tid >> 6, l = tid & 63;
  const int lr = l & 15, lg = l >> 4;
  const int frag = w ? (127 - f) : f;         // wave's 16-row fragment
  const int q0w = frag << 4;                  // first q row
  const size_t hqk = (size_t)bh * Tt * Dd;
  const __hip_bfloat16* qhp = Qhi + hqk;
  const __hip_bfloat16* qlp = Qlo + hqk;
  const __hip_bfloat16* khp = Khi + hqk;
  const __hip_bfloat16* klp = Klo + hqk;
  const __hip_bfloat16* vtp = VT + (size_t)bh * Dd * Tt;
  short* myP = &pbuf[w][0];

  s16x8 qh[2], ql[2];
#pragma unroll
  for (int df = 0; df < 2; ++df) {
    const size_t off = (size_t)(q0w + lr) * Dd + df * 32 + lg * 8;
    qh[df] = *reinterpret_cast<const s16x8*>(qhp + off);
    ql[df] = *reinterpret_cast<const s16x8*>(qlp + off);
  }

  f32x4 oacc[4];
  float mrow[4], lrow[4];
#pragma unroll
  for (int df = 0; df < 4; ++df) oacc[df] = f32x4{0.f, 0.f, 0.f, 0.f};
#pragma unroll
  for (int r = 0; r < 4; ++r) { mrow[r] = -__builtin_inff(); lrow[r] = 0.f; }

  const int ktmax = (q0w + 15) >> 6;
  for (int kt = 0; kt <= ktmax; ++kt) {
    const int k0 = kt << 6;
    const bool dotmask = (k0 + 63) > q0w;

    f32x4 s[4];
#pragma unroll
    for (int kjf = 0; kjf < 4; ++kjf) s[kjf] = f32x4{0.f, 0.f, 0.f, 0.f};
#pragma unroll
    for (int kjf = 0; kjf < 4; ++kjf) {
      const int krow = k0 + kjf * 16 + lr;
#pragma unroll
      for (int df = 0; df < 2; ++df) {
        const size_t off = (size_t)krow * Dd + df * 32 + lg * 8;
        const s16x8 kh = *reinterpret_cast<const s16x8*>(khp + off);
        const s16x8 kl = *reinterpret_cast<const s16x8*>(klp + off);
        s[kjf] = MFMA(qh[df], kh, s[kjf]);
        s[kjf] = MFMA(ql[df], kh, s[kjf]);
        s[kjf] = MFMA(qh[df], kl, s[kjf]);
      }
    }

#pragma unroll
    for (int r = 0; r < 4; ++r) {
      const int qi = q0w + lg * 4 + r;
      float mx = -__builtin_inff();
#pragma unroll
      for (int kjf = 0; kjf < 4; ++kjf) {
        float v = s[kjf][r] * 8.0f;
        if (dotmask && (k0 + kjf * 16 + lr) > qi) v = -__builtin_inff();
        s[kjf][r] = v;
        mx = fmaxf(mx, v);
      }
      mx = fmaxf(mx, __shfl_xor(mx, 1));
      mx = fmaxf(mx, __shfl_xor(mx, 2));
      mx = fmaxf(mx, __shfl_xor(mx, 4));
      mx = fmaxf(mx, __shfl_xor(mx, 8));
      const float mnew = fmaxf(mrow[r], mx);
      const float sc = __expf(mrow[r] - mnew);
      mrow[r] = mnew;
      float ls = 0.f;
#pragma unroll
      for (int kjf = 0; kjf < 4; ++kjf) {
        const float p = __expf(s[kjf][r] - mnew);
        s[kjf][r] = p;
        ls += p;
      }
      ls += __shfl_xor(ls, 1);
      ls += __shfl_xor(ls, 2);
      ls += __shfl_xor(ls, 4);
      ls += __shfl_xor(ls, 8);
      lrow[r] = lrow[r] * sc + ls;
#pragma unroll
      for (int df = 0; df < 4; ++df) oacc[df][r] *= sc;
    }

#pragma unroll
    for (int kjf = 0; kjf < 4; ++kjf)
#pragma unroll
      for (int r = 0; r < 4; ++r)
        myP[(lg * 4 + r) * 72 + kjf * 16 + lr] = f2bfbits(s[kjf][r]);

#pragma unroll
    for (int kf = 0; kf < 2; ++kf) {
      const s16x8 pa = *reinterpret_cast<const s16x8*>(myP + lr * 72 + kf * 32 + lg * 8);
#pragma unroll
      for (int df = 0; df < 4; ++df) {
        const s16x8 bv = *reinterpret_cast<const s16x8*>(
            vtp + (size_t)(df * 16 + lr) * Tt + k0 + kf * 32 + lg * 8);
        oacc[df] = MFMA(pa, bv, oacc[df]);
      }
    }
  }

#pragma unroll
  for (int df = 0; df < 4; ++df)
#pragma unroll
    for (int r = 0; r < 4; ++r) {
      const int t = q0w + lg * 4 + r;
      const int dc = df * 16 + lr;
      O[((size_t)b * Tt + t) * Cc + h * Dd + dc] =
          __float2bfloat16(oacc[df][r] / lrow[r]);
    }
}

// ---------------------------------------------------------------------------
extern "C" void kernel_launch(void* const* d_in, const int* in_sizes, int n_in,
                              void* d_out, int out_size, void* d_ws, size_t ws_size,
                              hipStream_t stream) {
  (void)in_sizes; (void)n_in; (void)out_size; (void)ws_size;
  const float* x  = (const float*)d_in[0];
  const float* wq = (const float*)d_in[1];
  const float* wk = (const float*)d_in[2];
  const float* wv = (const float*)d_in[3];
  const float* lm = (const float*)d_in[4];
  float* out = (float*)d_out;
  __hip_bfloat16* ws = (__hip_bfloat16*)d_ws;

  const size_t WSZ = (size_t)Cc * Cc;   // 589824
  const size_t TSZ = (size_t)Mm * Cc;   // 3145728
  __hip_bfloat16* WqThi = ws;
  __hip_bfloat16* WqTlo = WqThi + WSZ;
  __hip_bfloat16* WkThi = WqTlo + WSZ;
  __hip_bfloat16* WkTlo = WkThi + WSZ;
  __hip_bfloat16* WvThi = WkTlo + WSZ;
  __hip_bfloat16* LThi  = WvThi + WSZ;
  __hip_bfloat16* Xhi   = LThi + WSZ;
  __hip_bfloat16* Xlo   = Xhi + TSZ;
  __hip_bfloat16* Qhi   = Xlo + TSZ;
  __hip_bfloat16* Qlo   = Qhi + TSZ;
  __hip_bfloat16* Khi   = Qlo + TSZ;
  __hip_bfloat16* Klo   = Khi + TSZ;
  __hip_bfloat16* Vb    = Klo + TSZ;
  __hip_bfloat16* VT    = Vb + TSZ;
  __hip_bfloat16* Ob    = Vb;          // V dead after transpose_v; reuse for O

  prep_x<<<dim3(Mm * Cc / (256 * 8)), 256, 0, stream>>>(x, Xhi, Xlo);
  prep_w<<<dim3(12, 12, 4), 256, 0, stream>>>(wq, wk, wv, lm,
                                              WqThi, WqTlo, WkThi, WkTlo, WvThi, LThi);
  qkv_gemm<<<dim3(32, 6, 3), 256, 0, stream>>>(Xhi, Xlo, WqThi, WqTlo, WkThi, WkTlo,
                                               WvThi, Qhi, Qlo, Khi, Klo, Vb);
  transpose_v<<<dim3(32, BH), 256, 0, stream>>>(Vb, VT);
  attn_fwd<<<dim3(1536), 128, 0, stream>>>(Qhi, Qlo, Khi, Klo, VT, Ob);
  proj_gemm<<<dim3(32, 6), 256, 0, stream>>>(Ob, LThi, out);
}

// Round 6
// 201.225 us; speedup vs baseline: 1.0967x; 1.0967x over previous
//
#include <hip/hip_runtime.h>
#include <hip/hip_bf16.h>

// ---------------------------------------------------------------------------
// MultiHeadedMaskedSelfAttention (B=2,T=2048,C=768,H=12,D=64).
// I/O: float32. Compute: bf16 MFMA with hi/lo compensation on the
// softmax-critical path (x->Q/K and Q.K^T), plain bf16 elsewhere.
// attn_fwd v5 = round-4 structure (4-wave blocks, pair q-blocks {x,31-x},
// XCD-grouped heads) with REGISTER-BATCHED tile loads:
//   - 16 K hi/lo frag loads hoisted to tile start (one latency window)
//   - 8 V^T frag loads issued after QK MFMAs (latency hidden under softmax)
//   - __launch_bounds__(256,2) so the allocator can hold the batches
// ---------------------------------------------------------------------------

typedef float f32x4 __attribute__((ext_vector_type(4)));
typedef short s16x8 __attribute__((ext_vector_type(8)));

#define MFMA(a, b, c) __builtin_amdgcn_mfma_f32_16x16x32_bf16((a), (b), (c), 0, 0, 0)

constexpr int Bb = 2, Tt = 2048, Cc = 768, Hh = 12, Dd = 64;
constexpr int Mm = Bb * Tt;   // 4096
constexpr int BH = Bb * Hh;   // 24

__device__ __forceinline__ void gload16(const void* g, void* l) {
  __builtin_amdgcn_global_load_lds((const __attribute__((address_space(1))) void*)g,
                                   (__attribute__((address_space(3))) void*)l, 16, 0, 0);
}

__device__ __forceinline__ short f2bfbits(float f) {
  __hip_bfloat16 h = __float2bfloat16(f);
  return __builtin_bit_cast(short, h);
}
__device__ __forceinline__ float bf2f(short s) {
  __hip_bfloat16 h = __builtin_bit_cast(__hip_bfloat16, s);
  return __bfloat162float(h);
}

// ---------------------------------------------------------------------------
// prep_x: x f32 [4096][768] -> Xhi, Xlo bf16. grid(1536), 256 thr, 8 elts/thr.
// ---------------------------------------------------------------------------
__global__ __launch_bounds__(256) void prep_x(const float* __restrict__ x,
                                              __hip_bfloat16* __restrict__ xhi,
                                              __hip_bfloat16* __restrict__ xlo) {
  const size_t i = ((size_t)blockIdx.x * 256 + threadIdx.x) * 8;
  float4 a = *reinterpret_cast<const float4*>(x + i);
  float4 b = *reinterpret_cast<const float4*>(x + i + 4);
  float v[8] = {a.x, a.y, a.z, a.w, b.x, b.y, b.z, b.w};
  s16x8 hi, lo;
#pragma unroll
  for (int j = 0; j < 8; ++j) {
    short h = f2bfbits(v[j]);
    hi[j] = h;
    lo[j] = f2bfbits(v[j] - bf2f(h));
  }
  *reinterpret_cast<s16x8*>((short*)xhi + i) = hi;
  *reinterpret_cast<s16x8*>((short*)xlo + i) = lo;
}

// ---------------------------------------------------------------------------
// prep_w: f32 [768][768] -> transposed bf16. z=0: wq (hi+lo), z=1: wk (hi+lo),
// z=2: wv (hi), z=3: linear (hi). grid (12,12,4), 256 thr, 64x64 tiles.
// ---------------------------------------------------------------------------
__global__ __launch_bounds__(256) void prep_w(
    const float* __restrict__ s0, const float* __restrict__ s1,
    const float* __restrict__ s2, const float* __restrict__ s3,
    __hip_bfloat16* __restrict__ h0, __hip_bfloat16* __restrict__ l0,
    __hip_bfloat16* __restrict__ h1, __hip_bfloat16* __restrict__ l1,
    __hip_bfloat16* __restrict__ h2, __hip_bfloat16* __restrict__ h3) {
  const float* src;
  __hip_bfloat16 *dh, *dl = nullptr;
  switch (blockIdx.z) {
    case 0: src = s0; dh = h0; dl = l0; break;
    case 1: src = s1; dh = h1; dl = l1; break;
    case 2: src = s2; dh = h2; break;
    default: src = s3; dh = h3; break;
  }
  __shared__ float tile[64][65];
  const int r0 = blockIdx.y * 64, c0 = blockIdx.x * 64;
  const int tid = threadIdx.x;
  const int rr = tid >> 4, c4 = (tid & 15) * 4;
#pragma unroll
  for (int it = 0; it < 4; ++it) {
    float4 v = *reinterpret_cast<const float4*>(src + (size_t)(r0 + rr + it * 16) * Cc + c0 + c4);
    tile[rr + it * 16][c4 + 0] = v.x;
    tile[rr + it * 16][c4 + 1] = v.y;
    tile[rr + it * 16][c4 + 2] = v.z;
    tile[rr + it * 16][c4 + 3] = v.w;
  }
  __syncthreads();
#pragma unroll
  for (int it = 0; it < 2; ++it) {
    const int id = tid + it * 256;          // 0..511
    const int n = id >> 3, ch = (id & 7) * 8;
    s16x8 hi, lo;
#pragma unroll
    for (int j = 0; j < 8; ++j) {
      float v = tile[ch + j][n];
      short h = f2bfbits(v);
      hi[j] = h;
      lo[j] = f2bfbits(v - bf2f(h));
    }
    *reinterpret_cast<s16x8*>(dh + (size_t)(c0 + n) * Cc + r0 + ch) = hi;
    if (dl) *reinterpret_cast<s16x8*>(dl + (size_t)(c0 + n) * Cc + r0 + ch) = lo;
  }
}

// ---------------------------------------------------------------------------
// 128x128 GEMM cores. A[M,K] * Bt[N,K]^T, K=768, BK=32, 4 waves.
// ---------------------------------------------------------------------------
__device__ __forceinline__ void gemm128_core(const __hip_bfloat16* __restrict__ A,
                                             const __hip_bfloat16* __restrict__ Bt,
                                             int m0, int n0,
                                             short* ldsA, short* ldsB,
                                             f32x4 acc[4][4]) {
  const int tid = threadIdx.x;
  const int w = tid >> 6, l = tid & 63;
  const int wr = w >> 1, wc = w & 1;
  const int srow = l >> 2;
  const int scol = (l & 3) << 3;

  for (int kt = 0; kt < Cc / 32; ++kt) {
    const int kk = kt << 5;
#pragma unroll
    for (int i = 0; i < 2; ++i) {
      const int r = (w << 5) + (i << 4);
      gload16(A + (size_t)(m0 + r + srow) * Cc + kk + scol, ldsA + r * 32);
      gload16(Bt + (size_t)(n0 + r + srow) * Cc + kk + scol, ldsB + r * 32);
    }
    __syncthreads();
    s16x8 af[4], bfr[4];
#pragma unroll
    for (int i = 0; i < 4; ++i) {
      af[i]  = *reinterpret_cast<const s16x8*>(ldsA + ((wr << 6) + (i << 4) + (l & 15)) * 32 + ((l >> 4) << 3));
      bfr[i] = *reinterpret_cast<const s16x8*>(ldsB + ((wc << 6) + (i << 4) + (l & 15)) * 32 + ((l >> 4) << 3));
    }
#pragma unroll
    for (int i = 0; i < 4; ++i)
#pragma unroll
      for (int j = 0; j < 4; ++j)
        acc[i][j] = MFMA(af[i], bfr[j], acc[i][j]);
    __syncthreads();
  }
}

// hi/lo compensated: acc += Ahi*Bhi + (lo ? Ahi*Blo + Alo*Bhi : 0)
__device__ __forceinline__ void gemm128_hilo(
    const __hip_bfloat16* __restrict__ Ahi, const __hip_bfloat16* __restrict__ Alo,
    const __hip_bfloat16* __restrict__ Bhi, const __hip_bfloat16* __restrict__ Blo,
    bool lo, int m0, int n0, short* lds, f32x4 acc[4][4]) {
  short* ldsAh = lds;
  short* ldsAl = lds + 4096;
  short* ldsBh = lds + 8192;
  short* ldsBl = lds + 12288;
  const int tid = threadIdx.x;
  const int w = tid >> 6, l = tid & 63;
  const int wr = w >> 1, wc = w & 1;
  const int srow = l >> 2;
  const int scol = (l & 3) << 3;

  for (int kt = 0; kt < Cc / 32; ++kt) {
    const int kk = kt << 5;
#pragma unroll
    for (int i = 0; i < 2; ++i) {
      const int r = (w << 5) + (i << 4);
      const size_t aoff = (size_t)(m0 + r + srow) * Cc + kk + scol;
      const size_t boff = (size_t)(n0 + r + srow) * Cc + kk + scol;
      gload16(Ahi + aoff, ldsAh + r * 32);
      gload16(Bhi + boff, ldsBh + r * 32);
      if (lo) {
        gload16(Alo + aoff, ldsAl + r * 32);
        gload16(Blo + boff, ldsBl + r * 32);
      }
    }
    __syncthreads();
    s16x8 ah[4], bh[4], al[4], bl[4];
#pragma unroll
    for (int i = 0; i < 4; ++i) {
      const int ao = ((wr << 6) + (i << 4) + (l & 15)) * 32 + ((l >> 4) << 3);
      const int bo = ((wc << 6) + (i << 4) + (l & 15)) * 32 + ((l >> 4) << 3);
      ah[i] = *reinterpret_cast<const s16x8*>(ldsAh + ao);
      bh[i] = *reinterpret_cast<const s16x8*>(ldsBh + bo);
      if (lo) {
        al[i] = *reinterpret_cast<const s16x8*>(ldsAl + ao);
        bl[i] = *reinterpret_cast<const s16x8*>(ldsBl + bo);
      }
    }
#pragma unroll
    for (int i = 0; i < 4; ++i)
#pragma unroll
      for (int j = 0; j < 4; ++j)
        acc[i][j] = MFMA(ah[i], bh[j], acc[i][j]);
    if (lo) {
#pragma unroll
      for (int i = 0; i < 4; ++i)
#pragma unroll
        for (int j = 0; j < 4; ++j) {
          acc[i][j] = MFMA(ah[i], bl[j], acc[i][j]);
          acc[i][j] = MFMA(al[i], bh[j], acc[i][j]);
        }
    }
    __syncthreads();
  }
}

// ---------------------------------------------------------------------------
// QKV projection. grid (32, 6, 3): z=0 -> Q(hi,lo), z=1 -> K(hi,lo), z=2 -> V.
// Outputs in [B,H,T,D] layout.
// ---------------------------------------------------------------------------
__global__ __launch_bounds__(256) void qkv_gemm(
    const __hip_bfloat16* __restrict__ Xhi, const __hip_bfloat16* __restrict__ Xlo,
    const __hip_bfloat16* __restrict__ WqThi, const __hip_bfloat16* __restrict__ WqTlo,
    const __hip_bfloat16* __restrict__ WkThi, const __hip_bfloat16* __restrict__ WkTlo,
    const __hip_bfloat16* __restrict__ WvThi,
    __hip_bfloat16* __restrict__ Qhi, __hip_bfloat16* __restrict__ Qlo,
    __hip_bfloat16* __restrict__ Khi, __hip_bfloat16* __restrict__ Klo,
    __hip_bfloat16* __restrict__ V) {
  __shared__ __align__(16) short lds[16384];
  const int z = blockIdx.z;
  const bool lo = (z < 2);
  const __hip_bfloat16* Bhi = (z == 0) ? WqThi : (z == 1) ? WkThi : WvThi;
  const __hip_bfloat16* Blo = (z == 0) ? WqTlo : WkTlo;
  const int m0 = blockIdx.x * 128, n0 = blockIdx.y * 128;

  f32x4 acc[4][4];
#pragma unroll
  for (int i = 0; i < 4; ++i)
#pragma unroll
    for (int j = 0; j < 4; ++j) acc[i][j] = f32x4{0.f, 0.f, 0.f, 0.f};

  gemm128_hilo(Xhi, Xlo, Bhi, Blo, lo, m0, n0, lds, acc);

  const int tid = threadIdx.x, w = tid >> 6, l = tid & 63;
  const int wr = w >> 1, wc = w & 1;
#pragma unroll
  for (int i = 0; i < 4; ++i) {
#pragma unroll
    for (int j = 0; j < 4; ++j) {
#pragma unroll
      for (int r = 0; r < 4; ++r) {
        const int m = m0 + (wr << 6) + (i << 4) + ((l >> 4) << 2) + r;
        const int n = n0 + (wc << 6) + (j << 4) + (l & 15);
        const float v = acc[i][j][r];
        const int b = m >> 11, t = m & 2047, h = n >> 6, d = n & 63;
        const size_t idx = (((size_t)(b * Hh + h)) * Tt + t) * Dd + d;
        if (z == 2) {
          V[idx] = __float2bfloat16(v);
        } else {
          short hbits = f2bfbits(v);
          short lbits = f2bfbits(v - bf2f(hbits));
          if (z == 0) { ((short*)Qhi)[idx] = hbits; ((short*)Qlo)[idx] = lbits; }
          else        { ((short*)Khi)[idx] = hbits; ((short*)Klo)[idx] = lbits; }
        }
      }
    }
  }
}

// ---------------------------------------------------------------------------
// Output projection: out[M,C] (f32) = O[M,C](bf16) * LT[C,C]^T(bf16). grid(32,6)
// ---------------------------------------------------------------------------
__global__ __launch_bounds__(256) void proj_gemm(
    const __hip_bfloat16* __restrict__ O, const __hip_bfloat16* __restrict__ LT,
    float* __restrict__ out) {
  __shared__ __align__(16) short lds[8192];
  const int m0 = blockIdx.x * 128, n0 = blockIdx.y * 128;
  f32x4 acc[4][4];
#pragma unroll
  for (int i = 0; i < 4; ++i)
#pragma unroll
    for (int j = 0; j < 4; ++j) acc[i][j] = f32x4{0.f, 0.f, 0.f, 0.f};

  gemm128_core(O, LT, m0, n0, lds, lds + 4096, acc);

  const int tid = threadIdx.x, w = tid >> 6, l = tid & 63;
  const int wr = w >> 1, wc = w & 1;
#pragma unroll
  for (int i = 0; i < 4; ++i)
#pragma unroll
    for (int j = 0; j < 4; ++j)
#pragma unroll
      for (int r = 0; r < 4; ++r) {
        const int m = m0 + (wr << 6) + (i << 4) + ((l >> 4) << 2) + r;
        const int n = n0 + (wc << 6) + (j << 4) + (l & 15);
        out[(size_t)m * Cc + n] = acc[i][j][r];
      }
}

// ---------------------------------------------------------------------------
// V [BH][T][D] -> VT [BH][D][T].  grid (32, 24), 256 threads.
// ---------------------------------------------------------------------------
__global__ __launch_bounds__(256) void transpose_v(
    const __hip_bfloat16* __restrict__ V, __hip_bfloat16* __restrict__ VT) {
  __shared__ __align__(16) short tile[64][72];
  const int t0 = blockIdx.x * 64, bh = blockIdx.y;
  const __hip_bfloat16* src = V + (size_t)bh * Tt * Dd;
  __hip_bfloat16* dst = VT + (size_t)bh * Dd * Tt;
  const int tid = threadIdx.x;
  const int rr = tid >> 3;
  const int cc = (tid & 7) << 3;
#pragma unroll
  for (int it = 0; it < 2; ++it) {
    const int r = rr + it * 32;
    *reinterpret_cast<s16x8*>(&tile[r][cc]) =
        *reinterpret_cast<const s16x8*>(src + (size_t)(t0 + r) * Dd + cc);
  }
  __syncthreads();
#pragma unroll
  for (int it = 0; it < 2; ++it) {
    const int d = rr + it * 32;
    s16x8 o;
#pragma unroll
    for (int j = 0; j < 8; ++j) o[j] = tile[cc + j][d];
    *reinterpret_cast<s16x8*>(dst + (size_t)d * Tt + t0 + cc) = o;
  }
}

// ---------------------------------------------------------------------------
// Causal flash attention v5. grid (384) x 256 threads (4 waves).
// Block i: xcd = i&7 serves bh in {3*(i&7) .. +2}; x = (i>>3)&15.
// Waves 0,1 -> q-block x (halves 0,1); waves 2,3 -> q-block 31-x.
// Inner loop = round-4 verified body with loads hoisted into register
// batches (K at tile start, V after QK MFMAs) — value-identical.
// ---------------------------------------------------------------------------
__global__ __launch_bounds__(256, 2) void attn_fwd(
    const __hip_bfloat16* __restrict__ Qhi, const __hip_bfloat16* __restrict__ Qlo,
    const __hip_bfloat16* __restrict__ Khi, const __hip_bfloat16* __restrict__ Klo,
    const __hip_bfloat16* __restrict__ VT, __hip_bfloat16* __restrict__ O) {
  __shared__ __align__(16) short pbuf[4][32 * 72];
  const int i = blockIdx.x;
  const int g = i >> 3;                       // 0..47
  const int bh = (i & 7) * 3 + (g >> 4);      // 0..23
  const int x = g & 15;                       // 0..15
  const int b = bh / Hh, h = bh % Hh;
  const int tid = threadIdx.x, w = tid >> 6, l = tid & 63;
  const int lr = l & 15, lg = l >> 4;
  const int qblk = (w < 2) ? x : (31 - x);
  const int q0w = qblk * 64 + (w & 1) * 32;   // this wave's first q row
  const size_t hqk = (size_t)bh * Tt * Dd;
  const __hip_bfloat16* qhp = Qhi + hqk;
  const __hip_bfloat16* qlp = Qlo + hqk;
  const __hip_bfloat16* khp = Khi + hqk;
  const __hip_bfloat16* klp = Klo + hqk;
  const __hip_bfloat16* vtp = VT + (size_t)bh * Dd * Tt;
  short* myP = &pbuf[w][0];

  s16x8 qh[2][2], ql[2][2];
#pragma unroll
  for (int qf = 0; qf < 2; ++qf)
#pragma unroll
    for (int df = 0; df < 2; ++df) {
      const size_t off = (size_t)(q0w + qf * 16 + lr) * Dd + df * 32 + lg * 8;
      qh[qf][df] = *reinterpret_cast<const s16x8*>(qhp + off);
      ql[qf][df] = *reinterpret_cast<const s16x8*>(qlp + off);
    }

  f32x4 oacc[2][4];
  float mrow[2][4], lrow[2][4];
#pragma unroll
  for (int qf = 0; qf < 2; ++qf) {
#pragma unroll
    for (int df = 0; df < 4; ++df) oacc[qf][df] = f32x4{0.f, 0.f, 0.f, 0.f};
#pragma unroll
    for (int r = 0; r < 4; ++r) { mrow[qf][r] = -__builtin_inff(); lrow[qf][r] = 0.f; }
  }

  const int ktmax = (q0w + 31) >> 6;
  for (int kt = 0; kt <= ktmax; ++kt) {
    const int k0 = kt << 6;
    const bool dotmask = (k0 + 63) > q0w;

    // --- batched K-tile loads: 16 independent 16B loads, one latency window
    s16x8 kh[4][2], kl[4][2];
#pragma unroll
    for (int kjf = 0; kjf < 4; ++kjf)
#pragma unroll
      for (int df = 0; df < 2; ++df) {
        const size_t off = (size_t)(k0 + kjf * 16 + lr) * Dd + df * 32 + lg * 8;
        kh[kjf][df] = *reinterpret_cast<const s16x8*>(khp + off);
        kl[kjf][df] = *reinterpret_cast<const s16x8*>(klp + off);
      }

    // --- S = Q K^T (hi/lo compensated) ---
    f32x4 s[2][4];
#pragma unroll
    for (int qf = 0; qf < 2; ++qf)
#pragma unroll
      for (int kjf = 0; kjf < 4; ++kjf) s[qf][kjf] = f32x4{0.f, 0.f, 0.f, 0.f};
#pragma unroll
    for (int kjf = 0; kjf < 4; ++kjf)
#pragma unroll
      for (int df = 0; df < 2; ++df)
#pragma unroll
        for (int qf = 0; qf < 2; ++qf) {
          s[qf][kjf] = MFMA(qh[qf][df], kh[kjf][df], s[qf][kjf]);
          s[qf][kjf] = MFMA(ql[qf][df], kh[kjf][df], s[qf][kjf]);
          s[qf][kjf] = MFMA(qh[qf][df], kl[kjf][df], s[qf][kjf]);
        }

    // --- batched V-tile loads: independent of softmax, latency hides under it
    s16x8 bv[2][4];
#pragma unroll
    for (int kf = 0; kf < 2; ++kf)
#pragma unroll
      for (int df = 0; df < 4; ++df)
        bv[kf][df] = *reinterpret_cast<const s16x8*>(
            vtp + (size_t)(df * 16 + lr) * Tt + k0 + kf * 32 + lg * 8);

    // --- online softmax (identical to verified body) ---
#pragma unroll
    for (int qf = 0; qf < 2; ++qf) {
#pragma unroll
      for (int r = 0; r < 4; ++r) {
        const int qi = q0w + qf * 16 + lg * 4 + r;
        float mx = -__builtin_inff();
#pragma unroll
        for (int kjf = 0; kjf < 4; ++kjf) {
          float v = s[qf][kjf][r] * 8.0f;
          if (dotmask && (k0 + kjf * 16 + lr) > qi) v = -__builtin_inff();
          s[qf][kjf][r] = v;
          mx = fmaxf(mx, v);
        }
        mx = fmaxf(mx, __shfl_xor(mx, 1));
        mx = fmaxf(mx, __shfl_xor(mx, 2));
        mx = fmaxf(mx, __shfl_xor(mx, 4));
        mx = fmaxf(mx, __shfl_xor(mx, 8));
        const float mnew = fmaxf(mrow[qf][r], mx);
        const float sc = __expf(mrow[qf][r] - mnew);
        mrow[qf][r] = mnew;
        float ls = 0.f;
#pragma unroll
        for (int kjf = 0; kjf < 4; ++kjf) {
          const float p = __expf(s[qf][kjf][r] - mnew);
          s[qf][kjf][r] = p;
          ls += p;
        }
        ls += __shfl_xor(ls, 1);
        ls += __shfl_xor(ls, 2);
        ls += __shfl_xor(ls, 4);
        ls += __shfl_xor(ls, 8);
        lrow[qf][r] = lrow[qf][r] * sc + ls;
#pragma unroll
        for (int df = 0; df < 4; ++df) oacc[qf][df][r] *= sc;
      }
    }

    // --- P -> LDS (bf16), wave-private ---
#pragma unroll
    for (int qf = 0; qf < 2; ++qf)
#pragma unroll
      for (int kjf = 0; kjf < 4; ++kjf)
#pragma unroll
        for (int r = 0; r < 4; ++r)
          myP[(qf * 16 + lg * 4 + r) * 72 + kjf * 16 + lr] = f2bfbits(s[qf][kjf][r]);

    // --- O += P V (V frags already in registers) ---
#pragma unroll
    for (int kf = 0; kf < 2; ++kf) {
      s16x8 pa[2];
#pragma unroll
      for (int qf = 0; qf < 2; ++qf)
        pa[qf] = *reinterpret_cast<const s16x8*>(myP + (qf * 16 + lr) * 72 + kf * 32 + lg * 8);
#pragma unroll
      for (int df = 0; df < 4; ++df)
#pragma unroll
        for (int qf = 0; qf < 2; ++qf) oacc[qf][df] = MFMA(pa[qf], bv[kf][df], oacc[qf][df]);
    }
  }

#pragma unroll
  for (int qf = 0; qf < 2; ++qf)
#pragma unroll
    for (int df = 0; df < 4; ++df)
#pragma unroll
      for (int r = 0; r < 4; ++r) {
        const int t = q0w + qf * 16 + lg * 4 + r;
        const int dc = df * 16 + lr;
        O[((size_t)b * Tt + t) * Cc + h * Dd + dc] =
            __float2bfloat16(oacc[qf][df][r] / lrow[qf][r]);
      }
}

// ---------------------------------------------------------------------------
extern "C" void kernel_launch(void* const* d_in, const int* in_sizes, int n_in,
                              void* d_out, int out_size, void* d_ws, size_t ws_size,
                              hipStream_t stream) {
  (void)in_sizes; (void)n_in; (void)out_size; (void)ws_size;
  const float* x  = (const float*)d_in[0];
  const float* wq = (const float*)d_in[1];
  const float* wk = (const float*)d_in[2];
  const float* wv = (const float*)d_in[3];
  const float* lm = (const float*)d_in[4];
  float* out = (float*)d_out;
  __hip_bfloat16* ws = (__hip_bfloat16*)d_ws;

  const size_t WSZ = (size_t)Cc * Cc;   // 589824
  const size_t TSZ = (size_t)Mm * Cc;   // 3145728
  __hip_bfloat16* WqThi = ws;
  __hip_bfloat16* WqTlo = WqThi + WSZ;
  __hip_bfloat16* WkThi = WqTlo + WSZ;
  __hip_bfloat16* WkTlo = WkThi + WSZ;
  __hip_bfloat16* WvThi = WkTlo + WSZ;
  __hip_bfloat16* LThi  = WvThi + WSZ;
  __hip_bfloat16* Xhi   = LThi + WSZ;
  __hip_bfloat16* Xlo   = Xhi + TSZ;
  __hip_bfloat16* Qhi   = Xlo + TSZ;
  __hip_bfloat16* Qlo   = Qhi + TSZ;
  __hip_bfloat16* Khi   = Qlo + TSZ;
  __hip_bfloat16* Klo   = Khi + TSZ;
  __hip_bfloat16* Vb    = Klo + TSZ;
  __hip_bfloat16* VT    = Vb + TSZ;
  __hip_bfloat16* Ob    = Vb;          // V dead after transpose_v; reuse for O

  prep_x<<<dim3(Mm * Cc / (256 * 8)), 256, 0, stream>>>(x, Xhi, Xlo);
  prep_w<<<dim3(12, 12, 4), 256, 0, stream>>>(wq, wk, wv, lm,
                                              WqThi, WqTlo, WkThi, WkTlo, WvThi, LThi);
  qkv_gemm<<<dim3(32, 6, 3), 256, 0, stream>>>(Xhi, Xlo, WqThi, WqTlo, WkThi, WkTlo,
                                               WvThi, Qhi, Qlo, Khi, Klo, Vb);
  transpose_v<<<dim3(32, BH), 256, 0, stream>>>(Vb, VT);
  attn_fwd<<<dim3(384), 256, 0, stream>>>(Qhi, Qlo, Khi, Klo, VT, Ob);
  proj_gemm<<<dim3(32, 6), 256, 0, stream>>>(Ob, LThi, out);
}

// Round 7
// 174.072 us; speedup vs baseline: 1.2678x; 1.1560x over previous
//
#include <hip/hip_runtime.h>
#include <hip/hip_bf16.h>

// ---------------------------------------------------------------------------
// MultiHeadedMaskedSelfAttention (B=2,T=2048,C=768,H=12,D=64).
// I/O: float32. Compute: bf16 MFMA with hi/lo compensation on the
// softmax-critical path (x->Q/K and Q.K^T), plain bf16 elsewhere.
// attn_fwd v6: SWAPPED-OPERAND QK^T (mfma(K,Q)) so each lane's S column is
// its own q-row -> softmax is in-register (15 fmax + 2 shfl) with scalar
// m/l state; PV also swapped (mfma(V^T,P)) so O matches the same q=lr
// layout. K/Q/V global loads identical to the verified round-6 body.
// DS ops per tile: ~104 -> ~20.
// ---------------------------------------------------------------------------

typedef float f32x4 __attribute__((ext_vector_type(4)));
typedef short s16x8 __attribute__((ext_vector_type(8)));

#define MFMA(a, b, c) __builtin_amdgcn_mfma_f32_16x16x32_bf16((a), (b), (c), 0, 0, 0)

constexpr int Bb = 2, Tt = 2048, Cc = 768, Hh = 12, Dd = 64;
constexpr int Mm = Bb * Tt;   // 4096
constexpr int BH = Bb * Hh;   // 24

__device__ __forceinline__ void gload16(const void* g, void* l) {
  __builtin_amdgcn_global_load_lds((const __attribute__((address_space(1))) void*)g,
                                   (__attribute__((address_space(3))) void*)l, 16, 0, 0);
}

__device__ __forceinline__ short f2bfbits(float f) {
  __hip_bfloat16 h = __float2bfloat16(f);
  return __builtin_bit_cast(short, h);
}
__device__ __forceinline__ float bf2f(short s) {
  __hip_bfloat16 h = __builtin_bit_cast(__hip_bfloat16, s);
  return __bfloat162float(h);
}
__device__ __forceinline__ unsigned int packbf2(float a, float b) {
  return (unsigned int)(unsigned short)f2bfbits(a) |
         ((unsigned int)(unsigned short)f2bfbits(b) << 16);
}

// ---------------------------------------------------------------------------
// prep_x: x f32 [4096][768] -> Xhi, Xlo bf16. grid(1536), 256 thr, 8 elts/thr.
// ---------------------------------------------------------------------------
__global__ __launch_bounds__(256) void prep_x(const float* __restrict__ x,
                                              __hip_bfloat16* __restrict__ xhi,
                                              __hip_bfloat16* __restrict__ xlo) {
  const size_t i = ((size_t)blockIdx.x * 256 + threadIdx.x) * 8;
  float4 a = *reinterpret_cast<const float4*>(x + i);
  float4 b = *reinterpret_cast<const float4*>(x + i + 4);
  float v[8] = {a.x, a.y, a.z, a.w, b.x, b.y, b.z, b.w};
  s16x8 hi, lo;
#pragma unroll
  for (int j = 0; j < 8; ++j) {
    short h = f2bfbits(v[j]);
    hi[j] = h;
    lo[j] = f2bfbits(v[j] - bf2f(h));
  }
  *reinterpret_cast<s16x8*>((short*)xhi + i) = hi;
  *reinterpret_cast<s16x8*>((short*)xlo + i) = lo;
}

// ---------------------------------------------------------------------------
// prep_w: f32 [768][768] -> transposed bf16. z=0: wq (hi+lo), z=1: wk (hi+lo),
// z=2: wv (hi), z=3: linear (hi). grid (12,12,4), 256 thr, 64x64 tiles.
// ---------------------------------------------------------------------------
__global__ __launch_bounds__(256) void prep_w(
    const float* __restrict__ s0, const float* __restrict__ s1,
    const float* __restrict__ s2, const float* __restrict__ s3,
    __hip_bfloat16* __restrict__ h0, __hip_bfloat16* __restrict__ l0,
    __hip_bfloat16* __restrict__ h1, __hip_bfloat16* __restrict__ l1,
    __hip_bfloat16* __restrict__ h2, __hip_bfloat16* __restrict__ h3) {
  const float* src;
  __hip_bfloat16 *dh, *dl = nullptr;
  switch (blockIdx.z) {
    case 0: src = s0; dh = h0; dl = l0; break;
    case 1: src = s1; dh = h1; dl = l1; break;
    case 2: src = s2; dh = h2; break;
    default: src = s3; dh = h3; break;
  }
  __shared__ float tile[64][65];
  const int r0 = blockIdx.y * 64, c0 = blockIdx.x * 64;
  const int tid = threadIdx.x;
  const int rr = tid >> 4, c4 = (tid & 15) * 4;
#pragma unroll
  for (int it = 0; it < 4; ++it) {
    float4 v = *reinterpret_cast<const float4*>(src + (size_t)(r0 + rr + it * 16) * Cc + c0 + c4);
    tile[rr + it * 16][c4 + 0] = v.x;
    tile[rr + it * 16][c4 + 1] = v.y;
    tile[rr + it * 16][c4 + 2] = v.z;
    tile[rr + it * 16][c4 + 3] = v.w;
  }
  __syncthreads();
#pragma unroll
  for (int it = 0; it < 2; ++it) {
    const int id = tid + it * 256;          // 0..511
    const int n = id >> 3, ch = (id & 7) * 8;
    s16x8 hi, lo;
#pragma unroll
    for (int j = 0; j < 8; ++j) {
      float v = tile[ch + j][n];
      short h = f2bfbits(v);
      hi[j] = h;
      lo[j] = f2bfbits(v - bf2f(h));
    }
    *reinterpret_cast<s16x8*>(dh + (size_t)(c0 + n) * Cc + r0 + ch) = hi;
    if (dl) *reinterpret_cast<s16x8*>(dl + (size_t)(c0 + n) * Cc + r0 + ch) = lo;
  }
}

// ---------------------------------------------------------------------------
// 128x128 GEMM cores. A[M,K] * Bt[N,K]^T, K=768, BK=32, 4 waves.
// ---------------------------------------------------------------------------
__device__ __forceinline__ void gemm128_core(const __hip_bfloat16* __restrict__ A,
                                             const __hip_bfloat16* __restrict__ Bt,
                                             int m0, int n0,
                                             short* ldsA, short* ldsB,
                                             f32x4 acc[4][4]) {
  const int tid = threadIdx.x;
  const int w = tid >> 6, l = tid & 63;
  const int wr = w >> 1, wc = w & 1;
  const int srow = l >> 2;
  const int scol = (l & 3) << 3;

  for (int kt = 0; kt < Cc / 32; ++kt) {
    const int kk = kt << 5;
#pragma unroll
    for (int i = 0; i < 2; ++i) {
      const int r = (w << 5) + (i << 4);
      gload16(A + (size_t)(m0 + r + srow) * Cc + kk + scol, ldsA + r * 32);
      gload16(Bt + (size_t)(n0 + r + srow) * Cc + kk + scol, ldsB + r * 32);
    }
    __syncthreads();
    s16x8 af[4], bfr[4];
#pragma unroll
    for (int i = 0; i < 4; ++i) {
      af[i]  = *reinterpret_cast<const s16x8*>(ldsA + ((wr << 6) + (i << 4) + (l & 15)) * 32 + ((l >> 4) << 3));
      bfr[i] = *reinterpret_cast<const s16x8*>(ldsB + ((wc << 6) + (i << 4) + (l & 15)) * 32 + ((l >> 4) << 3));
    }
#pragma unroll
    for (int i = 0; i < 4; ++i)
#pragma unroll
      for (int j = 0; j < 4; ++j)
        acc[i][j] = MFMA(af[i], bfr[j], acc[i][j]);
    __syncthreads();
  }
}

// hi/lo compensated: acc += Ahi*Bhi + (lo ? Ahi*Blo + Alo*Bhi : 0)
__device__ __forceinline__ void gemm128_hilo(
    const __hip_bfloat16* __restrict__ Ahi, const __hip_bfloat16* __restrict__ Alo,
    const __hip_bfloat16* __restrict__ Bhi, const __hip_bfloat16* __restrict__ Blo,
    bool lo, int m0, int n0, short* lds, f32x4 acc[4][4]) {
  short* ldsAh = lds;
  short* ldsAl = lds + 4096;
  short* ldsBh = lds + 8192;
  short* ldsBl = lds + 12288;
  const int tid = threadIdx.x;
  const int w = tid >> 6, l = tid & 63;
  const int wr = w >> 1, wc = w & 1;
  const int srow = l >> 2;
  const int scol = (l & 3) << 3;

  for (int kt = 0; kt < Cc / 32; ++kt) {
    const int kk = kt << 5;
#pragma unroll
    for (int i = 0; i < 2; ++i) {
      const int r = (w << 5) + (i << 4);
      const size_t aoff = (size_t)(m0 + r + srow) * Cc + kk + scol;
      const size_t boff = (size_t)(n0 + r + srow) * Cc + kk + scol;
      gload16(Ahi + aoff, ldsAh + r * 32);
      gload16(Bhi + boff, ldsBh + r * 32);
      if (lo) {
        gload16(Alo + aoff, ldsAl + r * 32);
        gload16(Blo + boff, ldsBl + r * 32);
      }
    }
    __syncthreads();
    s16x8 ah[4], bh[4], al[4], bl[4];
#pragma unroll
    for (int i = 0; i < 4; ++i) {
      const int ao = ((wr << 6) + (i << 4) + (l & 15)) * 32 + ((l >> 4) << 3);
      const int bo = ((wc << 6) + (i << 4) + (l & 15)) * 32 + ((l >> 4) << 3);
      ah[i] = *reinterpret_cast<const s16x8*>(ldsAh + ao);
      bh[i] = *reinterpret_cast<const s16x8*>(ldsBh + bo);
      if (lo) {
        al[i] = *reinterpret_cast<const s16x8*>(ldsAl + ao);
        bl[i] = *reinterpret_cast<const s16x8*>(ldsBl + bo);
      }
    }
#pragma unroll
    for (int i = 0; i < 4; ++i)
#pragma unroll
      for (int j = 0; j < 4; ++j)
        acc[i][j] = MFMA(ah[i], bh[j], acc[i][j]);
    if (lo) {
#pragma unroll
      for (int i = 0; i < 4; ++i)
#pragma unroll
        for (int j = 0; j < 4; ++j) {
          acc[i][j] = MFMA(ah[i], bl[j], acc[i][j]);
          acc[i][j] = MFMA(al[i], bh[j], acc[i][j]);
        }
    }
    __syncthreads();
  }
}

// ---------------------------------------------------------------------------
// QKV projection. grid (32, 6, 3): z=0 -> Q(hi,lo), z=1 -> K(hi,lo), z=2 -> V.
// Outputs in [B,H,T,D] layout.
// ---------------------------------------------------------------------------
__global__ __launch_bounds__(256) void qkv_gemm(
    const __hip_bfloat16* __restrict__ Xhi, const __hip_bfloat16* __restrict__ Xlo,
    const __hip_bfloat16* __restrict__ WqThi, const __hip_bfloat16* __restrict__ WqTlo,
    const __hip_bfloat16* __restrict__ WkThi, const __hip_bfloat16* __restrict__ WkTlo,
    const __hip_bfloat16* __restrict__ WvThi,
    __hip_bfloat16* __restrict__ Qhi, __hip_bfloat16* __restrict__ Qlo,
    __hip_bfloat16* __restrict__ Khi, __hip_bfloat16* __restrict__ Klo,
    __hip_bfloat16* __restrict__ V) {
  __shared__ __align__(16) short lds[16384];
  const int z = blockIdx.z;
  const bool lo = (z < 2);
  const __hip_bfloat16* Bhi = (z == 0) ? WqThi : (z == 1) ? WkThi : WvThi;
  const __hip_bfloat16* Blo = (z == 0) ? WqTlo : WkTlo;
  const int m0 = blockIdx.x * 128, n0 = blockIdx.y * 128;

  f32x4 acc[4][4];
#pragma unroll
  for (int i = 0; i < 4; ++i)
#pragma unroll
    for (int j = 0; j < 4; ++j) acc[i][j] = f32x4{0.f, 0.f, 0.f, 0.f};

  gemm128_hilo(Xhi, Xlo, Bhi, Blo, lo, m0, n0, lds, acc);

  const int tid = threadIdx.x, w = tid >> 6, l = tid & 63;
  const int wr = w >> 1, wc = w & 1;
#pragma unroll
  for (int i = 0; i < 4; ++i) {
#pragma unroll
    for (int j = 0; j < 4; ++j) {
#pragma unroll
      for (int r = 0; r < 4; ++r) {
        const int m = m0 + (wr << 6) + (i << 4) + ((l >> 4) << 2) + r;
        const int n = n0 + (wc << 6) + (j << 4) + (l & 15);
        const float v = acc[i][j][r];
        const int b = m >> 11, t = m & 2047, h = n >> 6, d = n & 63;
        const size_t idx = (((size_t)(b * Hh + h)) * Tt + t) * Dd + d;
        if (z == 2) {
          V[idx] = __float2bfloat16(v);
        } else {
          short hbits = f2bfbits(v);
          short lbits = f2bfbits(v - bf2f(hbits));
          if (z == 0) { ((short*)Qhi)[idx] = hbits; ((short*)Qlo)[idx] = lbits; }
          else        { ((short*)Khi)[idx] = hbits; ((short*)Klo)[idx] = lbits; }
        }
      }
    }
  }
}

// ---------------------------------------------------------------------------
// Output projection: out[M,C] (f32) = O[M,C](bf16) * LT[C,C]^T(bf16). grid(32,6)
// ---------------------------------------------------------------------------
__global__ __launch_bounds__(256) void proj_gemm(
    const __hip_bfloat16* __restrict__ O, const __hip_bfloat16* __restrict__ LT,
    float* __restrict__ out) {
  __shared__ __align__(16) short lds[8192];
  const int m0 = blockIdx.x * 128, n0 = blockIdx.y * 128;
  f32x4 acc[4][4];
#pragma unroll
  for (int i = 0; i < 4; ++i)
#pragma unroll
    for (int j = 0; j < 4; ++j) acc[i][j] = f32x4{0.f, 0.f, 0.f, 0.f};

  gemm128_core(O, LT, m0, n0, lds, lds + 4096, acc);

  const int tid = threadIdx.x, w = tid >> 6, l = tid & 63;
  const int wr = w >> 1, wc = w & 1;
#pragma unroll
  for (int i = 0; i < 4; ++i)
#pragma unroll
    for (int j = 0; j < 4; ++j)
#pragma unroll
      for (int r = 0; r < 4; ++r) {
        const int m = m0 + (wr << 6) + (i << 4) + ((l >> 4) << 2) + r;
        const int n = n0 + (wc << 6) + (j << 4) + (l & 15);
        out[(size_t)m * Cc + n] = acc[i][j][r];
      }
}

// ---------------------------------------------------------------------------
// V [BH][T][D] -> VT [BH][D][T].  grid (32, 24), 256 threads.
// ---------------------------------------------------------------------------
__global__ __launch_bounds__(256) void transpose_v(
    const __hip_bfloat16* __restrict__ V, __hip_bfloat16* __restrict__ VT) {
  __shared__ __align__(16) short tile[64][72];
  const int t0 = blockIdx.x * 64, bh = blockIdx.y;
  const __hip_bfloat16* src = V + (size_t)bh * Tt * Dd;
  __hip_bfloat16* dst = VT + (size_t)bh * Dd * Tt;
  const int tid = threadIdx.x;
  const int rr = tid >> 3;
  const int cc = (tid & 7) << 3;
#pragma unroll
  for (int it = 0; it < 2; ++it) {
    const int r = rr + it * 32;
    *reinterpret_cast<s16x8*>(&tile[r][cc]) =
        *reinterpret_cast<const s16x8*>(src + (size_t)(t0 + r) * Dd + cc);
  }
  __syncthreads();
#pragma unroll
  for (int it = 0; it < 2; ++it) {
    const int d = rr + it * 32;
    s16x8 o;
#pragma unroll
    for (int j = 0; j < 8; ++j) o[j] = tile[cc + j][d];
    *reinterpret_cast<s16x8*>(dst + (size_t)d * Tt + t0 + cc) = o;
  }
}

// ---------------------------------------------------------------------------
// Causal flash attention v6 (swapped operands). grid (384) x 256 thr (4 waves).
// Block i: xcd = i&7 serves bh in {3*(i&7) .. +2}; x = (i>>3)&15.
// Waves 0,1 -> q-block x (halves 0,1); waves 2,3 -> q-block 31-x.
// S frag (qf,kjf): s[r] = S[k = k0+kjf*16+lg*4+r][q = q0w+qf*16+lr]
// O frag (qf,df): oacc[r] = O[q = q0w+qf*16+lr][d = df*16+lg*4+r]
// Softmax: per-thread over 16 regs + shfl_xor(16,32); m/l scalar per qf.
// ---------------------------------------------------------------------------
__global__ __launch_bounds__(256, 2) void attn_fwd(
    const __hip_bfloat16* __restrict__ Qhi, const __hip_bfloat16* __restrict__ Qlo,
    const __hip_bfloat16* __restrict__ Khi, const __hip_bfloat16* __restrict__ Klo,
    const __hip_bfloat16* __restrict__ VT, __hip_bfloat16* __restrict__ O) {
  __shared__ __align__(16) short pbuf[4][32 * 72];
  const int i = blockIdx.x;
  const int g = i >> 3;                       // 0..47
  const int bh = (i & 7) * 3 + (g >> 4);      // 0..23
  const int x = g & 15;                       // 0..15
  const int b = bh / Hh, h = bh % Hh;
  const int tid = threadIdx.x, w = tid >> 6, l = tid & 63;
  const int lr = l & 15, lg = l >> 4;
  const int qblk = (w < 2) ? x : (31 - x);
  const int q0w = qblk * 64 + (w & 1) * 32;   // this wave's first q row
  const size_t hqk = (size_t)bh * Tt * Dd;
  const __hip_bfloat16* qhp = Qhi + hqk;
  const __hip_bfloat16* qlp = Qlo + hqk;
  const __hip_bfloat16* khp = Khi + hqk;
  const __hip_bfloat16* klp = Klo + hqk;
  const __hip_bfloat16* vtp = VT + (size_t)bh * Dd * Tt;
  short* myP = &pbuf[w][0];

  // Q fragments (B-operand: col = lr = q), loads identical to round 6.
  s16x8 qh[2][2], ql[2][2];
#pragma unroll
  for (int qf = 0; qf < 2; ++qf)
#pragma unroll
    for (int df = 0; df < 2; ++df) {
      const size_t off = (size_t)(q0w + qf * 16 + lr) * Dd + df * 32 + lg * 8;
      qh[qf][df] = *reinterpret_cast<const s16x8*>(qhp + off);
      ql[qf][df] = *reinterpret_cast<const s16x8*>(qlp + off);
    }

  f32x4 oacc[2][4];
  float mrow[2], lrow[2];
#pragma unroll
  for (int qf = 0; qf < 2; ++qf) {
#pragma unroll
    for (int df = 0; df < 4; ++df) oacc[qf][df] = f32x4{0.f, 0.f, 0.f, 0.f};
    mrow[qf] = -__builtin_inff();
    lrow[qf] = 0.f;
  }

  const int ktmax = (q0w + 31) >> 6;
  for (int kt = 0; kt <= ktmax; ++kt) {
    const int k0 = kt << 6;
    const bool dotmask = (k0 + 63) > q0w;

    // K fragment loads (A-operand: row = lr = k), identical to round 6.
    s16x8 kh[4][2], kl[4][2];
#pragma unroll
    for (int kjf = 0; kjf < 4; ++kjf)
#pragma unroll
      for (int df = 0; df < 2; ++df) {
        const size_t off = (size_t)(k0 + kjf * 16 + lr) * Dd + df * 32 + lg * 8;
        kh[kjf][df] = *reinterpret_cast<const s16x8*>(khp + off);
        kl[kjf][df] = *reinterpret_cast<const s16x8*>(klp + off);
      }

    // --- S^T = K Q^T (swapped; hi/lo compensated) ---
    f32x4 s[2][4];
#pragma unroll
    for (int qf = 0; qf < 2; ++qf)
#pragma unroll
      for (int kjf = 0; kjf < 4; ++kjf) s[qf][kjf] = f32x4{0.f, 0.f, 0.f, 0.f};
#pragma unroll
    for (int kjf = 0; kjf < 4; ++kjf)
#pragma unroll
      for (int df = 0; df < 2; ++df)
#pragma unroll
        for (int qf = 0; qf < 2; ++qf) {
          s[qf][kjf] = MFMA(kh[kjf][df], qh[qf][df], s[qf][kjf]);
          s[qf][kjf] = MFMA(kl[kjf][df], qh[qf][df], s[qf][kjf]);
          s[qf][kjf] = MFMA(kh[kjf][df], ql[qf][df], s[qf][kjf]);
        }

    // V^T fragment loads (A-operand: row = lr = d), identical to round 6.
    s16x8 bv[2][4];
#pragma unroll
    for (int kf = 0; kf < 2; ++kf)
#pragma unroll
      for (int df = 0; df < 4; ++df)
        bv[kf][df] = *reinterpret_cast<const s16x8*>(
            vtp + (size_t)(df * 16 + lr) * Tt + k0 + kf * 32 + lg * 8);

    // --- in-register online softmax (per qf; this thread's q = q0w+qf*16+lr)
#pragma unroll
    for (int qf = 0; qf < 2; ++qf) {
      const int q = q0w + qf * 16 + lr;
      float mx = -__builtin_inff();
#pragma unroll
      for (int kjf = 0; kjf < 4; ++kjf)
#pragma unroll
        for (int r = 0; r < 4; ++r) {
          float v = s[qf][kjf][r] * 8.0f;
          if (dotmask && (k0 + kjf * 16 + lg * 4 + r) > q) v = -__builtin_inff();
          s[qf][kjf][r] = v;
          mx = fmaxf(mx, v);
        }
      mx = fmaxf(mx, __shfl_xor(mx, 16));
      mx = fmaxf(mx, __shfl_xor(mx, 32));
      const float mnew = fmaxf(mrow[qf], mx);
      const float sc = __expf(mrow[qf] - mnew);
      mrow[qf] = mnew;
      float ls = 0.f;
#pragma unroll
      for (int kjf = 0; kjf < 4; ++kjf)
#pragma unroll
        for (int r = 0; r < 4; ++r) {
          const float p = __expf(s[qf][kjf][r] - mnew);
          s[qf][kjf][r] = p;
          ls += p;
        }
      ls += __shfl_xor(ls, 16);
      ls += __shfl_xor(ls, 32);
      lrow[qf] = lrow[qf] * sc + ls;
#pragma unroll
      for (int df = 0; df < 4; ++df) oacc[qf][df] *= sc;
    }

    // --- P -> LDS as [q][k] bf16 (packed b64 writes), wave-private ---
#pragma unroll
    for (int qf = 0; qf < 2; ++qf)
#pragma unroll
      for (int kjf = 0; kjf < 4; ++kjf) {
        uint2 pk;
        pk.x = packbf2(s[qf][kjf][0], s[qf][kjf][1]);
        pk.y = packbf2(s[qf][kjf][2], s[qf][kjf][3]);
        *reinterpret_cast<uint2*>(myP + (qf * 16 + lr) * 72 + kjf * 16 + lg * 4) = pk;
      }

    // --- O^T += V^T P^T (swapped): oacc[qf][df] row=d(lg*4+r), col=q(lr) ---
#pragma unroll
    for (int kf = 0; kf < 2; ++kf) {
      s16x8 pa[2];
#pragma unroll
      for (int qf = 0; qf < 2; ++qf)
        pa[qf] = *reinterpret_cast<const s16x8*>(myP + (qf * 16 + lr) * 72 + kf * 32 + lg * 8);
#pragma unroll
      for (int df = 0; df < 4; ++df)
#pragma unroll
        for (int qf = 0; qf < 2; ++qf)
          oacc[qf][df] = MFMA(bv[kf][df], pa[qf], oacc[qf][df]);
    }
  }

  // --- epilogue: O[b][t=q][h*64+d], d = df*16+lg*4+r, packed 8B stores ---
#pragma unroll
  for (int qf = 0; qf < 2; ++qf) {
    const float inv = 1.0f / lrow[qf];
    const int t = q0w + qf * 16 + lr;
#pragma unroll
    for (int df = 0; df < 4; ++df) {
      uint2 pk;
      pk.x = packbf2(oacc[qf][df][0] * inv, oacc[qf][df][1] * inv);
      pk.y = packbf2(oacc[qf][df][2] * inv, oacc[qf][df][3] * inv);
      *reinterpret_cast<uint2*>(
          (short*)O + ((size_t)b * Tt + t) * Cc + h * Dd + df * 16 + lg * 4) = pk;
    }
  }
}

// ---------------------------------------------------------------------------
extern "C" void kernel_launch(void* const* d_in, const int* in_sizes, int n_in,
                              void* d_out, int out_size, void* d_ws, size_t ws_size,
                              hipStream_t stream) {
  (void)in_sizes; (void)n_in; (void)out_size; (void)ws_size;
  const float* x  = (const float*)d_in[0];
  const float* wq = (const float*)d_in[1];
  const float* wk = (const float*)d_in[2];
  const float* wv = (const float*)d_in[3];
  const float* lm = (const float*)d_in[4];
  float* out = (float*)d_out;
  __hip_bfloat16* ws = (__hip_bfloat16*)d_ws;

  const size_t WSZ = (size_t)Cc * Cc;   // 589824
  const size_t TSZ = (size_t)Mm * Cc;   // 3145728
  __hip_bfloat16* WqThi = ws;
  __hip_bfloat16* WqTlo = WqThi + WSZ;
  __hip_bfloat16* WkThi = WqTlo + WSZ;
  __hip_bfloat16* WkTlo = WkThi + WSZ;
  __hip_bfloat16* WvThi = WkTlo + WSZ;
  __hip_bfloat16* LThi  = WvThi + WSZ;
  __hip_bfloat16* Xhi   = LThi + WSZ;
  __hip_bfloat16* Xlo   = Xhi + TSZ;
  __hip_bfloat16* Qhi   = Xlo + TSZ;
  __hip_bfloat16* Qlo   = Qhi + TSZ;
  __hip_bfloat16* Khi   = Qlo + TSZ;
  __hip_bfloat16* Klo   = Khi + TSZ;
  __hip_bfloat16* Vb    = Klo + TSZ;
  __hip_bfloat16* VT    = Vb + TSZ;
  __hip_bfloat16* Ob    = Vb;          // V dead after transpose_v; reuse for O

  prep_x<<<dim3(Mm * Cc / (256 * 8)), 256, 0, stream>>>(x, Xhi, Xlo);
  prep_w<<<dim3(12, 12, 4), 256, 0, stream>>>(wq, wk, wv, lm,
                                              WqThi, WqTlo, WkThi, WkTlo, WvThi, LThi);
  qkv_gemm<<<dim3(32, 6, 3), 256, 0, stream>>>(Xhi, Xlo, WqThi, WqTlo, WkThi, WkTlo,
                                               WvThi, Qhi, Qlo, Khi, Klo, Vb);
  transpose_v<<<dim3(32, BH), 256, 0, stream>>>(Vb, VT);
  attn_fwd<<<dim3(384), 256, 0, stream>>>(Qhi, Qlo, Khi, Klo, VT, Ob);
  proj_gemm<<<dim3(32, 6), 256, 0, stream>>>(Ob, LThi, out);
}